// Round 19
// baseline (95.919 us; speedup 1.0000x reference)
//
#include <hip/hip_runtime.h>
#include <cstdint>
#include <cstddef>

// ---------------- problem constants ----------------
#define BATCH 16
#define NBOX 25200
#define NCH 85          // 4 box + 1 obj + 80 cls
#define KPRE 1024
#define MAXDET 1000
#define NCAND_MAX 4096
#define CSHIFT 12       // cutoff compare domain: k >> 12
#define HB 4096         // LDS histogram buckets
#define HBASE 0x40800   // (k>>12) of the highest valid score (~1.0); valid span = 4096
#define IDX_PAD 0xFFFFFFFFu

__device__ __forceinline__ unsigned key_of(float s) {
    // monotone map: larger score -> SMALLER key (ascending sort = descending score)
    unsigned u = __float_as_uint(s);
    unsigned m = (u & 0x80000000u) ? ~u : (u | 0x80000000u);
    return ~m;
}

// ---------------- kernel 1: per-box max score, 4 lanes x TWO boxes (2x MLP), NO atomics ----------------
// Each 4-lane group handles boxes 2p,2p+1. Every lane issues 10 independent float4 loads
// (both boxes) before any reduce -> 2x in-flight bytes vs R17. Line-contiguous per group.
__global__ __launch_bounds__(256) void score_kernel(const float* __restrict__ x,
                                                    unsigned* __restrict__ k32) {
    int gid = blockIdx.x * 256 + threadIdx.x;
    int pr = gid >> 2;                                // pair index
    int q = gid & 3;
    int boxA = pr * 2;
    const float* rowA = x + (size_t)boxA * NCH;
    const float* rowB = rowA + NCH;

    const float4* pA = (const float4*)rowA;           // 4B-aligned vector loads
    const float4* pB = (const float4*)rowB;
    // issue all 10 chunk loads + 4 broadcast tails up front (independent)
    float4 a0 = pA[q], a1 = pA[q + 4], a2 = pA[q + 8], a3 = pA[q + 12], a4 = pA[q + 16];
    float4 b0 = pB[q], b1 = pB[q + 4], b2 = pB[q + 8], b3 = pB[q + 12], b4 = pB[q + 16];
    float4 at = pA[20]; float ac79 = rowA[84]; float objA = rowA[4];
    float4 bt = pB[20]; float bc79 = rowB[84]; float objB = rowB[4];

    // mask non-class floats in chunk 0: q==0 -> floats 0..3 (box), q==1 -> float 4 (obj)
    if (q == 0) { a0.x = a0.y = a0.z = a0.w = -1e30f; b0.x = b0.y = b0.z = b0.w = -1e30f; }
    if (q == 1) { a0.x = -1e30f; b0.x = -1e30f; }

    float va = fmaxf(fmaxf(a0.x, a0.y), fmaxf(a0.z, a0.w));
    va = fmaxf(va, fmaxf(fmaxf(a1.x, a1.y), fmaxf(a1.z, a1.w)));
    va = fmaxf(va, fmaxf(fmaxf(a2.x, a2.y), fmaxf(a2.z, a2.w)));
    va = fmaxf(va, fmaxf(fmaxf(a3.x, a3.y), fmaxf(a3.z, a3.w)));
    va = fmaxf(va, fmaxf(fmaxf(a4.x, a4.y), fmaxf(a4.z, a4.w)));
    va = fmaxf(va, fmaxf(fmaxf(at.x, at.y), fmaxf(at.z, at.w)));
    va = fmaxf(va, ac79);
    float vb = fmaxf(fmaxf(b0.x, b0.y), fmaxf(b0.z, b0.w));
    vb = fmaxf(vb, fmaxf(fmaxf(b1.x, b1.y), fmaxf(b1.z, b1.w)));
    vb = fmaxf(vb, fmaxf(fmaxf(b2.x, b2.y), fmaxf(b2.z, b2.w)));
    vb = fmaxf(vb, fmaxf(fmaxf(b3.x, b3.y), fmaxf(b3.z, b3.w)));
    vb = fmaxf(vb, fmaxf(fmaxf(b4.x, b4.y), fmaxf(b4.z, b4.w)));
    vb = fmaxf(vb, fmaxf(fmaxf(bt.x, bt.y), fmaxf(bt.z, bt.w)));
    vb = fmaxf(vb, bc79);

    va = fmaxf(va, __shfl_xor(va, 1)); va = fmaxf(va, __shfl_xor(va, 2));
    vb = fmaxf(vb, __shfl_xor(vb, 1)); vb = fmaxf(vb, __shfl_xor(vb, 2));

    if (q == 0) {
        float confA = objA * va;                      // = max(cls*obj) exactly (monotone mul)
        float confB = objB * vb;
        bool vA = (objA > 0.25f) && (confA > 0.25f);
        bool vB = (objB > 0.25f) && (confB > 0.25f);
        uint2 out;
        out.x = key_of(vA ? confA : -1.0f);
        out.y = key_of(vB ? confB : -1.0f);
        *(uint2*)(k32 + boxA) = out;                  // boxA even -> 8B aligned
    }
}

// ---------------- kernel 2: fused hist+cutoff + compaction + bitonic sort + decode ----------------
__global__ __launch_bounds__(1024) void sort_gather(const unsigned* __restrict__ k32,
                                                    float* __restrict__ topconf,
                                                    unsigned* __restrict__ topidx) {
    __shared__ unsigned long long keys[NCAND_MAX];   // 32 KB
    __shared__ unsigned h[HB];                       // 16 KB
    __shared__ unsigned part[1024];
    __shared__ unsigned wsum[16];
    __shared__ unsigned cnt[25][16];
    __shared__ unsigned waveOff[25][16];
    __shared__ unsigned chunkBase[25];
    __shared__ unsigned totc[25];
    __shared__ unsigned cutP, nTot;
    int b = blockIdx.x, t = threadIdx.x;
    int lane = t & 63, wv = t >> 6;
    const unsigned* kb = k32 + (size_t)b * NBOX;

    // ---- load all keys into registers (25 coalesced loads in flight) ----
    unsigned kreg[25];
    unsigned validbits = 0;
    #pragma unroll
    for (int c = 0; c < 25; c++) {
        int i = c * 1024 + t;
        unsigned k = 0x80000000u;                    // invalid sentinel for tail
        if (i < NBOX) k = kb[i];
        kreg[c] = k;
        validbits |= (((int)k >= 0) ? 1u : 0u) << c;
    }

    // ---- LDS histogram over valid keys ----
    #pragma unroll
    for (int j = 0; j < HB / 1024; j++) h[t + j * 1024] = 0;
    __syncthreads();
    #pragma unroll
    for (int c = 0; c < 25; c++) {
        if ((validbits >> c) & 1u) {
            int bu = (int)(kreg[c] >> CSHIFT) - HBASE;
            bu = bu < 0 ? 0 : (bu > HB - 1 ? HB - 1 : bu);
            atomicAdd(&h[bu], 1u);                   // LDS atomic, ~4.6 entries/bucket
        }
    }
    __syncthreads();

    // ---- cutoff covering rank KPRE ----
    {
        unsigned s = h[4 * t] + h[4 * t + 1] + h[4 * t + 2] + h[4 * t + 3];
        part[t] = s;
        unsigned ws = s;
        #pragma unroll
        for (int off = 1; off < 64; off <<= 1) ws += __shfl_xor(ws, off);
        if (lane == 0) wsum[wv] = ws;
    }
    __syncthreads();
    if (t == 0) {
        unsigned cum = 0; int W = -1;
        for (int w = 0; w < 16; w++)
            if (W < 0) { if (cum + wsum[w] >= KPRE) W = w; else cum += wsum[w]; }
        int T = -1;
        if (W >= 0)
            for (int i = 0; i < 64; i++)
                if (T < 0) { int p = W * 64 + i; if (cum + part[p] >= KPRE) T = p; else cum += part[p]; }
        unsigned P = HB - 1;                         // fewer than KPRE valid -> take all valid
        if (T >= 0)
            for (int j = 0; j < 4; j++) { cum += h[T * 4 + j]; if (cum >= KPRE) { P = (unsigned)(T * 4 + j); break; } }
        cutP = P + HBASE;                            // compare domain: (k >> CSHIFT) <= cutP
    }
    __syncthreads();
    unsigned P = cutP;

    // ---- deterministic index-ordered compaction (ballot count matrix) ----
    unsigned passbits = 0;
    #pragma unroll
    for (int c = 0; c < 25; c++) {
        bool p = ((validbits >> c) & 1u) && ((kreg[c] >> CSHIFT) <= P);
        passbits |= (p ? 1u : 0u) << c;
    }
    #pragma unroll
    for (int c = 0; c < 25; c++) {
        unsigned long long m = __ballot((passbits >> c) & 1u);
        if (lane == 0) cnt[c][wv] = (unsigned)__popcll(m);
    }
    __syncthreads();
    if (t < 25) {
        unsigned run = 0;
        #pragma unroll
        for (int w2 = 0; w2 < 16; w2++) { waveOff[t][w2] = run; run += cnt[t][w2]; }
        totc[t] = run;
    }
    __syncthreads();
    if (t == 0) {
        unsigned acc = 0;
        for (int c = 0; c < 25; c++) { chunkBase[c] = acc; acc += totc[c]; }
        nTot = acc;
    }
    __syncthreads();
    int n = (int)nTot; if (n > NCAND_MAX) n = NCAND_MAX;
    #pragma unroll
    for (int c = 0; c < 25; c++) {
        unsigned long long m = __ballot((passbits >> c) & 1u);
        if ((passbits >> c) & 1u) {
            unsigned rank = chunkBase[c] + waveOff[c][wv] +
                            (unsigned)__popcll(lane ? (m & ((~0ull) >> (64 - lane))) : 0ull);
            if (rank < NCAND_MAX)
                keys[rank] = ((unsigned long long)kreg[c] << 32) | (unsigned)(c * 1024 + t);
        }
    }
    int m2 = 2048;                                   // fast path always sorts 2048
    while (m2 < n) m2 <<= 1;
    int nq = m2 >> 10;
    for (int q = 0; q < nq; q++) { int s2 = t + (q << 10); if (s2 >= n) keys[s2] = ~0ull; }
    __syncthreads();

    unsigned long long myKey;
    if (m2 == 2048) {
        // ---- fast 2048-element bitonic: 2 elems/thread, shfl for j<=32 ----
        const int i0 = t, i1 = t + 1024;
        unsigned long long e0 = keys[i0], e1 = keys[i1];
        #pragma unroll
        for (int k = 2; k <= 64; k <<= 1) {          // 21 passes, zero barriers
            #pragma unroll
            for (int j = k >> 1; j > 0; j >>= 1) {
                unsigned long long p0 = __shfl_xor(e0, j);
                unsigned long long p1 = __shfl_xor(e1, j);
                bool sel0 = ((i0 & k) == 0) != ((i0 & j) != 0);
                bool sel1 = ((i1 & k) == 0) != ((i1 & j) != 0);
                e0 = sel0 ? (e0 < p0 ? e0 : p0) : (e0 > p0 ? e0 : p0);
                e1 = sel1 ? (e1 < p1 ? e1 : p1) : (e1 > p1 ? e1 : p1);
            }
        }
        for (int k = 128; k <= 2048; k <<= 1) {
            keys[i0] = e0; keys[i1] = e1;
            __syncthreads();
            for (int j = k >> 1; j >= 64; j >>= 1) { // LDS passes (j crosses waves)
                #pragma unroll
                for (int q = 0; q < 2; q++) {
                    int i = t + (q << 10);
                    int ixj = i ^ j;
                    if (ixj > i) {
                        unsigned long long a = keys[i], bb2 = keys[ixj];
                        bool up = ((i & k) == 0);
                        if ((a > bb2) == up) { keys[i] = bb2; keys[ixj] = a; }
                    }
                }
                __syncthreads();
            }
            e0 = keys[i0]; e1 = keys[i1];
            #pragma unroll
            for (int j = 32; j > 0; j >>= 1) {       // in-wave tail, zero barriers
                unsigned long long p0 = __shfl_xor(e0, j);
                unsigned long long p1 = __shfl_xor(e1, j);
                bool sel0 = ((i0 & k) == 0) != ((i0 & j) != 0);
                bool sel1 = ((i1 & k) == 0) != ((i1 & j) != 0);
                e0 = sel0 ? (e0 < p0 ? e0 : p0) : (e0 > p0 ? e0 : p0);
                e1 = sel1 ? (e1 < p1 ? e1 : p1) : (e1 > p1 ? e1 : p1);
            }
        }
        myKey = e0;                                  // position t = rank t, straight from reg
    } else {
        // ---- generic fallback (n > 2048; unreachable for this data, kept for correctness) ----
        for (int k = 2; k <= m2; k <<= 1) {
            for (int j = k >> 1; j > 0; j >>= 1) {
                for (int q = 0; q < nq; q++) {
                    int i = t + (q << 10);
                    int ixj = i ^ j;
                    if (ixj > i) {
                        unsigned long long a = keys[i], bb2 = keys[ixj];
                        bool up = ((i & k) == 0);
                        if ((a > bb2) == up) { keys[i] = bb2; keys[ixj] = a; }
                    }
                }
                __syncthreads();
            }
        }
        myKey = keys[t];
    }

    // ---- decode rank t ----
    int o = (b << 10) + t;
    if (t < n) {
        unsigned kk = (unsigned)(myKey >> 32);
        unsigned mm = ~kk;
        unsigned bits = (mm & 0x80000000u) ? (mm & 0x7FFFFFFFu) : ~mm;
        topconf[o] = __uint_as_float(bits);     // exact original score
        topidx[o] = (unsigned)(myKey & 0xFFFFFFFFu);
    } else {
        topconf[o] = -1.0f;
        topidx[o] = IDX_PAD;
    }
}

// ---------------- kernel 3: exact argmax + box build for the 16K survivors only ----------------
__global__ __launch_bounds__(256) void argmax_gather(const float* __restrict__ x,
                                                     const unsigned* __restrict__ topidx,
                                                     float4* __restrict__ topbox,
                                                     float4* __restrict__ topoff,
                                                     float* __restrict__ topcls) {
#pragma clang fp contract(off)
    int gid = blockIdx.x * 256 + threadIdx.x;
    int o = gid >> 2;                           // entry in [0, BATCH*KPRE)
    int q = gid & 3;
    int b = o >> 10;
    unsigned idx = topidx[o];

    float4 box = make_float4(0.f, 0.f, 0.f, 0.f);
    float clsf = 0.f;
    if (idx != IDX_PAD) {
        size_t base = ((size_t)b * NBOX + idx) * NCH;
        float obj = x[base + 4];
        int cbase = 5 + q * 20;
        float v = -1e30f; int c = 0;
        #pragma unroll
        for (int j = 0; j < 20; j++) {
            float s = x[base + cbase + j] * obj;
            if (s > v) { v = s; c = q * 20 + j; }      // strict > = first occurrence
        }
        #pragma unroll
        for (int off = 1; off <= 2; off <<= 1) {
            float ov = __shfl_xor(v, off);
            int   oc = __shfl_xor(c, off);
            if (ov > v || (ov == v && oc < c)) { v = ov; c = oc; }
        }
        if (q == 0) {
            float cx = x[base + 0], cy = x[base + 1], w = x[base + 2], h = x[base + 3];
            box = make_float4(cx - w * 0.5f, cy - h * 0.5f, cx + w * 0.5f, cy + h * 0.5f);
            clsf = (float)c;
        }
    }
    if (q == 0) {
        topbox[o] = box;
        topcls[o] = clsf;
        float off = clsf * 4096.0f;
        topoff[o] = make_float4(box.x + off, box.y + off, box.z + off, box.w + off);
    }
}

// ---------------- kernel 4: pairwise IoU bitmask, TRANSPOSED LDS (conflict-free) ----------------
__global__ __launch_bounds__(256) void iou_mask(const float4* __restrict__ topoff,
                                                unsigned long long* __restrict__ mask,
                                                unsigned short* __restrict__ summ) {
#pragma clang fp contract(off)
    __shared__ float4 soff[KPRE];
    int b = blockIdx.x >> 6;
    int blk = blockIdx.x & 63;
    int t = threadIdx.x;
    // contiguous LDS slots (no write conflict); permuted global read still 16 lines/instr
    for (int q = 0; q < 4; q++) {
        int u = t + q * 256;                       // LDS slot
        int s = ((u & 15) << 6) | (u >> 4);        // source box = invperm(u)
        soff[u] = topoff[(b << 10) + s];
    }
    __syncthreads();
    int i = (blk << 4) + (t >> 4);
    int w = t & 15;
    unsigned long long bits = 0;
    int jbase = w << 6;
    if (jbase + 63 > i) {                          // lower-triangle words are identically 0
        float4 a = soff[((i & 63) << 4) | (i >> 6)];
        float area_a = (a.z - a.x) * (a.w - a.y);
        for (int jj = 0; jj < 64; jj++) {
            int j = jbase + jj;
            float4 bb = soff[(jj << 4) | w];       // transposed slot for box j
            float area_b = (bb.z - bb.x) * (bb.w - bb.y);
            float ltx = fmaxf(a.x, bb.x), lty = fmaxf(a.y, bb.y);
            float rbx = fminf(a.z, bb.z), rby = fminf(a.w, bb.w);
            float wx = fmaxf(rbx - ltx, 0.0f), wy = fmaxf(rby - lty, 0.0f);
            float inter = wx * wy;
            float iou = inter / (area_a + area_b - inter + 1e-7f);
            if (j > i && iou > 0.45f) bits |= (1ull << jj);
        }
    }
    mask[((size_t)((b << 10) + i) << 4) + w] = bits;
    unsigned long long bal = __ballot(bits != 0ull);
    if (w == 0) {
        int l = t & 63;
        summ[(b << 10) + i] = (unsigned short)((bal >> ((l >> 4) << 4)) & 0xFFFFull);
    }
}

// ---------------- kernel 5: greedy suppression + ordered output (1 block / batch) ----------------
__global__ __launch_bounds__(1024) void nms_finalize(const unsigned long long* __restrict__ mask,
                                                     const unsigned short* __restrict__ summ,
                                                     const float* __restrict__ topconf,
                                                     const float4* __restrict__ topbox,
                                                     const float* __restrict__ topcls,
                                                     float* __restrict__ dets,
                                                     float* __restrict__ vmask) {
    __shared__ unsigned long long kb[16];
    int b = blockIdx.x, tid = threadIdx.x;

    if (tid < 64) {
        int lane = tid;
        const unsigned long long* mrow = mask + ((size_t)b << 14);
        unsigned long long keep0[16];
        #pragma unroll
        for (int c = 0; c < 16; c++) {
            float cf = topconf[(b << 10) + (c << 6) + lane];
            keep0[c] = __ballot(cf > 0.0f);
        }
        unsigned nz[16];
        #pragma unroll
        for (int t = 0; t < 16; t++)
            nz[t] = (unsigned)summ[(b << 10) + (t << 6) + lane];
        unsigned long long diag[16];
        #pragma unroll
        for (int t = 0; t < 16; t++)
            diag[t] = mrow[((size_t)((t << 6) + lane) << 4) + t];

        unsigned long long remv[16];
        #pragma unroll
        for (int t = 0; t < 16; t++) remv[t] = 0;

        #pragma unroll
        for (int t = 0; t < 16; t++) {
            unsigned long long live = keep0[t] & ~remv[t];
            unsigned long long kept = live;
            unsigned long long pend = live & __ballot((nz[t] >> t) & 1u);
            while (pend) {
                int j = (int)__ffsll(pend) - 1;
                pend &= pend - 1;
                if ((kept >> j) & 1ull) {
                    unsigned long long dj = __shfl(diag[t], j);
                    kept &= ~dj;
                    pend &= ~dj;
                }
            }
            if (lane == 0) kb[t] = kept;

            #pragma unroll
            for (int w = 0; w < 16; w++) {
                if (w > t) {
                    unsigned long long wm = kept & __ballot((nz[t] >> w) & 1u);
                    while (wm) {
                        int j = (int)__ffsll(wm) - 1;
                        wm &= wm - 1;
                        remv[w] |= mrow[((size_t)((t << 6) + j) << 4) + w];
                    }
                }
            }
        }
    }
    __syncthreads();

    int r = tid;
    int w = r >> 6, l = r & 63;
    unsigned long long word = kb[w];
    int keep = (int)((word >> l) & 1ull);
    int base = 0, total = 0;
    #pragma unroll
    for (int q = 0; q < 16; q++) {
        int c = __popcll(kb[q]);
        total += c;
        if (q < w) base += c;
    }
    int rank = base + __popcll((l == 0) ? 0ull : (word & ((~0ull) >> (64 - l))));
    float* drow = dets + (size_t)b * (MAXDET * 6);
    float* vm = vmask + (size_t)b * MAXDET;
    if (r < MAXDET && r >= total) {
#pragma unroll
        for (int cc = 0; cc < 6; cc++) drow[r * 6 + cc] = 0.0f;
        vm[r] = 0.0f;
    }
    if (keep && rank < MAXDET) {
        int o = (b << 10) + r;
        float4 bx = topbox[o];
        drow[rank * 6 + 0] = bx.x;
        drow[rank * 6 + 1] = bx.y;
        drow[rank * 6 + 2] = bx.z;
        drow[rank * 6 + 3] = bx.w;
        drow[rank * 6 + 4] = topconf[o];
        drow[rank * 6 + 5] = topcls[o];
        vm[rank] = 1.0f;
    }
}

// ---------------- launcher ----------------
extern "C" void kernel_launch(void* const* d_in, const int* in_sizes, int n_in,
                              void* d_out, int out_size, void* d_ws, size_t ws_size,
                              hipStream_t stream) {
    const float* x = (const float*)d_in[0];
    char* w = (char*)d_ws;

    // workspace layout (bytes), total 4,463,616
    unsigned long long* mask    = (unsigned long long*)(w + 0);        // 2,097,152
    unsigned*           k32     = (unsigned*)(w + 2097152);            // 1,612,800
    float4*             topbox  = (float4*)(w + 3709952);              // 262,144
    float4*             topoff  = (float4*)(w + 3972096);              // 262,144
    float*              topconf = (float*)(w + 4234240);               // 65,536
    float*              topcls  = (float*)(w + 4299776);               // 65,536
    unsigned*           topidx  = (unsigned*)(w + 4365312);            // 65,536
    unsigned short*     summ    = (unsigned short*)(w + 4430848);      // 32,768
    if (ws_size < 4463616) return;  // insufficient scratch -> deterministic failure

    score_kernel<<<(BATCH * NBOX * 2) / 256, 256, 0, stream>>>(x, k32);
    sort_gather<<<BATCH, 1024, 0, stream>>>(k32, topconf, topidx);
    argmax_gather<<<(BATCH * KPRE * 4) / 256, 256, 0, stream>>>(x, topidx, topbox, topoff, topcls);
    iou_mask<<<BATCH * 64, 256, 0, stream>>>(topoff, mask, summ);

    float* dets = (float*)d_out;
    float* vmask = dets + (size_t)BATCH * MAXDET * 6;
    nms_finalize<<<BATCH, 1024, 0, stream>>>(mask, summ, topconf, topbox, topcls, dets, vmask);
}